// Round 9
// baseline (299.745 us; speedup 1.0000x reference)
//
#include <hip/hip_runtime.h>

typedef unsigned short u16;
using u16x4  = __attribute__((ext_vector_type(4))) unsigned short;
using u16x8  = __attribute__((ext_vector_type(8))) unsigned short;
using bf16x8 = __attribute__((ext_vector_type(8))) short;
using f32x4  = __attribute__((ext_vector_type(4))) float;
using f32x16 = __attribute__((ext_vector_type(16))) float;

// ---------- helpers ----------
__device__ __forceinline__ unsigned cvt_pk_bf16(float a, float b) {
  unsigned d;
  asm("v_cvt_pk_bf16_f32 %0, %1, %2" : "=v"(d) : "v"(a), "v"(b));
  return d;  // low16 = bf16(a), high16 = bf16(b)
}

// ---------- pre-pass (LDS-free, W only): W [mat][i][h] fp32 -> blocked bf16 ----------
// layout: element (i,h) -> (i>>4)*4096 + h*16 + (i&15)
// thread (bid,t): mat = bid>>4, ib = bid&15, h = t. 16 coalesced row-reads
// (nontemporal: fp32 W never re-read), cvt_pk pack, 32 B contiguous write.
__global__ __launch_bounds__(256) void prepass_k(
    const float* __restrict__ W1, const float* __restrict__ W2,
    u16* __restrict__ w1t, u16* __restrict__ w2t) {
  const int bid = blockIdx.x;
  const int t = threadIdx.x;
  const int mat = bid >> 4;            // 0..511
  const int ib  = bid & 15;            // i-block (16 rows)
  const float* src = (mat < 256) ? (W1 + mat * 65536) : (W2 + (mat - 256) * 65536);
  u16*       dst   = (mat < 256) ? (w1t + mat * 65536) : (w2t + (mat - 256) * 65536);
  const int i0 = ib * 16;

  float r[16];
#pragma unroll
  for (int j = 0; j < 16; ++j)
    r[j] = __builtin_nontemporal_load(src + (i0 + j) * 256 + t);

  uint4 lo, hi;
  lo.x = cvt_pk_bf16(r[0],  r[1]);  lo.y = cvt_pk_bf16(r[2],  r[3]);
  lo.z = cvt_pk_bf16(r[4],  r[5]);  lo.w = cvt_pk_bf16(r[6],  r[7]);
  hi.x = cvt_pk_bf16(r[8],  r[9]);  hi.y = cvt_pk_bf16(r[10], r[11]);
  hi.z = cvt_pk_bf16(r[12], r[13]); hi.w = cvt_pk_bf16(r[14], r[15]);
  u16* o = dst + ib * 4096 + t * 16;   // (i>>4)*4096 + h*16 + (i&15)
  *(uint4*)(o)     = lo;               // i&15 = 0..7
  *(uint4*)(o + 8) = hi;               // i&15 = 8..15
}

// ---------- main fused kernel: 4-wave blocks, 64-row tiles, 4 blocks/CU ----------
// Identical per-CU per-chunk pipe totals to R8 (A-VMEM 32 KB, 32 ds_read_b128,
// 128 MFMA) but 4 independent blocks/CU instead of 2: barrier scope is 4 waves,
// so one block's serial staging/epilogue overlaps 3 other blocks' K-loops.
// Block = (subcarrier c, 64-row batch tile). 4 waves = 4 wq; wave = 2 m-frags
// (m_base = wq*64, +0/+32) x 2 n-frags (rows 0-31 / 32-63).
// x staged DIRECTLY from fp32 with inline cvt_pk (xb prepass eliminated; x is
// L2/L3-resident). A depth-2 register pipeline (3 rotating sets), B ping-pong,
// setprio around MFMA clusters, R7 set-alignment (phase B consumes aS[(ch+1)%3]).
// DO NOT make blocks persistent (R5: L2 thrash, FETCH 38->508 MB).
// LDS: 64*264*2 + 2 KB red = 35.8 KB -> 4 blocks/CU. Regs ~124 combined <= 128.
__global__ __launch_bounds__(256, 4) void rf_main_k(
    const float* __restrict__ x, const u16* __restrict__ w1t, const u16* __restrict__ w2t,
    const float* __restrict__ b1, const float* __restrict__ b2,
    const float* __restrict__ w3, const float* __restrict__ b3,
    float* __restrict__ out) {
  __shared__ u16 sH[64 * 264];         // x-tile, then H1 (in place), stride 264
  __shared__ float red[8 * 64];

  const int bid  = blockIdx.x;         // 8192 blocks
  const int xcd  = bid & 7;
  const int j8   = bid >> 3;           // 0..1023; consecutive j8 = same c
  const int c    = xcd * 32 + (j8 >> 5);
  const int b0   = (j8 & 31) * 64;
  const int t    = threadIdx.x;
  const int lane = t & 63;
  const int wq   = t >> 6;             // 4 waves = 4 m-positions
  const int l31  = lane & 31;
  const int hi   = lane >> 5;
  const bool hiH = hi != 0;
  const int m_base = wq * 64;

  const u16* w1c = w1t + c * 65536;
  const u16* w2c = w2t + c * 65536;
  const int aoff  = (m_base + l31) * 16 + hi * 8;          // + ch*4096 + mi*512
  const int bbase = l31 * 264 + hi * 8;                    // + ch*16 (+8448 for nj=1)
  const int bidx  = __builtin_amdgcn_readfirstlane(c * 256 + m_base);

  f32x16 acc[2][2];
  bf16x8 aS[3][2];                     // A rotating sets, depth 2
  bf16x8 bS[2][2];                     // B ping-pong, depth 1

#define LOADA(dst, base)                                         \
  { dst[0] = *(const bf16x8*)(base);                             \
    dst[1] = *(const bf16x8*)((base) + 512); }

#define LOADB(dst, ch)                                           \
  { dst[0] = *(const bf16x8*)&sH[bbase + (ch) * 16];             \
    dst[1] = *(const bf16x8*)&sH[bbase + (ch) * 16 + 8448]; }

#define COMPUTE(afr, bfr)                                        \
  { __builtin_amdgcn_s_setprio(1);                               \
    acc[0][0] = __builtin_amdgcn_mfma_f32_32x32x16_bf16(afr[0], bfr[0], acc[0][0], 0, 0, 0); \
    acc[1][0] = __builtin_amdgcn_mfma_f32_32x32x16_bf16(afr[1], bfr[0], acc[1][0], 0, 0, 0); \
    acc[0][1] = __builtin_amdgcn_mfma_f32_32x32x16_bf16(afr[0], bfr[1], acc[0][1], 0, 0, 0); \
    acc[1][1] = __builtin_amdgcn_mfma_f32_32x32x16_bf16(afr[1], bfr[1], acc[1][1], 0, 0, 0); \
    __builtin_amdgcn_s_setprio(0); }

#define INIT_ACC(bp)                                             \
  { _Pragma("unroll")                                            \
    for (int _mi = 0; _mi < 2; ++_mi) {                          \
      _Pragma("unroll")                                          \
      for (int _g = 0; _g < 4; ++_g) {                           \
        f32x4 _lo = *(const f32x4*)((bp) + bidx + _mi * 32 + _g * 8);     \
        f32x4 _h4 = *(const f32x4*)((bp) + bidx + _mi * 32 + _g * 8 + 4); \
        _Pragma("unroll")                                        \
        for (int _r = 0; _r < 4; ++_r) {                         \
          float _v = hiH ? _h4[_r] : _lo[_r];                    \
          acc[_mi][0][_g * 4 + _r] = _v;                         \
          acc[_mi][1][_g * 4 + _r] = _v;                         \
        } } } }

  // ---- prologue: A chunks 0,1 of W1 in flight; stage x (inline fp32->bf16) ----
  LOADA(aS[0], w1c + 0 * 4096 + aoff);
  LOADA(aS[1], w1c + 1 * 4096 + aoff);

#pragma unroll
  for (int i = 0; i < 8; ++i) {
    int flat = i * 256 + t;
    int r = flat >> 5, s = flat & 31;  // row r, 8-col group s
    const float* xp = x + (b0 + r) * 256 + s * 8;
    float4 f0 = *(const float4*)(xp);
    float4 f1 = *(const float4*)(xp + 4);
    uint4 p;
    p.x = cvt_pk_bf16(f0.x, f0.y); p.y = cvt_pk_bf16(f0.z, f0.w);
    p.z = cvt_pk_bf16(f1.x, f1.y); p.w = cvt_pk_bf16(f1.z, f1.w);
    *(uint4*)&sH[r * 264 + s * 8] = p;
  }
  INIT_ACC(b1);
  __syncthreads();

  // ========== Phase A: H1^T = W1^T . x^T (+b1, relu), barrier-free K-loop ==========
  // prologue ch0->aS[0], ch1->aS[1]; consume aS[ch%3], load ch+2 -> aS[(ch+2)%3];
  // tail (ch=14,15) prefetches W2 chunk 0->aS[1], chunk 1->aS[2].
  LOADB(bS[0], 0);
#pragma unroll
  for (int ch = 0; ch < 16; ++ch) {
    const u16* ab = (ch + 2 < 16) ? (w1c + (ch + 2) * 4096) : (w2c + (ch - 14) * 4096);
    LOADA(aS[(ch + 2) % 3], ab + aoff);
    if (ch + 1 < 16) LOADB(bS[(ch + 1) & 1], ch + 1);
    COMPUTE(aS[ch % 3], bS[ch & 1]);
  }

  // Phase A epilogue: relu -> bf16 H1, in place over sX (b64 stores, in-lane packing)
  __syncthreads();                     // all x reads retired
#pragma unroll
  for (int mi = 0; mi < 2; ++mi)
#pragma unroll
    for (int nj = 0; nj < 2; ++nj) {
      const int row = nj * 32 + l31;
#pragma unroll
      for (int g = 0; g < 4; ++g) {
        float v0 = fmaxf(acc[mi][nj][g * 4 + 0], 0.f);
        float v1 = fmaxf(acc[mi][nj][g * 4 + 1], 0.f);
        float v2 = fmaxf(acc[mi][nj][g * 4 + 2], 0.f);
        float v3 = fmaxf(acc[mi][nj][g * 4 + 3], 0.f);
        uint2 p;
        p.x = cvt_pk_bf16(v0, v1);
        p.y = cvt_pk_bf16(v2, v3);
        *(uint2*)&sH[row * 264 + m_base + mi * 32 + g * 8 + 4 * hi] = p;
      }
    }
  INIT_ACC(b2);
  __syncthreads();                     // H1 published

  // ========== Phase B: H2^T = W2^T . H1^T (+b2, relu), then in-lane dot W3 ==========
  // W2 chunk j lives in aS[(j+1)%3] -> consume aS[(ch+1)%3], prefetch ch+2 -> aS[ch%3].
  LOADB(bS[0], 0);
#pragma unroll
  for (int ch = 0; ch < 16; ++ch) {
    if (ch + 2 < 16) LOADA(aS[ch % 3], w2c + (ch + 2) * 4096 + aoff);
    if (ch + 1 < 16) LOADB(bS[(ch + 1) & 1], ch + 1);
    COMPUTE(aS[(ch + 1) % 3], bS[ch & 1]);
  }

  // Phase B epilogue: out-col reduction fully in-lane (w3 wave-uniform per reg)
  float part0 = 0.f, part1 = 0.f;
#pragma unroll
  for (int mi = 0; mi < 2; ++mi)
#pragma unroll
    for (int g = 0; g < 4; ++g) {
      f32x4 wlo = *(const f32x4*)(w3 + bidx + mi * 32 + g * 8);
      f32x4 whi = *(const f32x4*)(w3 + bidx + mi * 32 + g * 8 + 4);
#pragma unroll
      for (int r = 0; r < 4; ++r) {
        float wv = hiH ? whi[r] : wlo[r];
        part0 += fmaxf(acc[mi][0][g * 4 + r], 0.f) * wv;
        part1 += fmaxf(acc[mi][1][g * 4 + r], 0.f) * wv;
      }
    }
  red[(wq * 2 + hi) * 64 + l31]      = part0;
  red[(wq * 2 + hi) * 64 + 32 + l31] = part1;
  __syncthreads();
  if (t < 64) {
    float v = b3[c];
#pragma unroll
    for (int k = 0; k < 8; ++k) v += red[k * 64 + t];
    out[(b0 + t) * 256 + c] = v;
  }
#undef LOADA
#undef LOADB
#undef COMPUTE
#undef INIT_ACC
}

// ---------- launcher ----------
extern "C" void kernel_launch(void* const* d_in, const int* in_sizes, int n_in,
                              void* d_out, int out_size, void* d_ws, size_t ws_size,
                              hipStream_t stream) {
  const float* x  = (const float*)d_in[0];
  const float* W1 = (const float*)d_in[1];
  const float* b1 = (const float*)d_in[2];
  const float* W2 = (const float*)d_in[3];
  const float* b2 = (const float*)d_in[4];
  const float* W3 = (const float*)d_in[5];
  const float* b3 = (const float*)d_in[6];
  float* out = (float*)d_out;

  char* ws = (char*)d_ws;
  u16* w1t = (u16*)ws;                                   // 32 MB
  u16* w2t = (u16*)(ws + (32u << 20));                   // 32 MB

  prepass_k <<<8192, 256, 0, stream>>>(W1, W2, w1t, w2t);
  rf_main_k <<<8192, 256, 0, stream>>>(x, w1t, w2t, b1, b2, W3, b3, out);
}